// Round 1
// baseline (188.102 us; speedup 1.0000x reference)
//
#include <hip/hip_runtime.h>
#include <math.h>

#define ALPHA   0.2f
#define B_DIM   8
#define N_NODES 1024
#define FIN     64
#define T_DIM   8
#define O_DIM   128
#define MAXN    256

// ---------------------------------------------------------------------------
// Kernel 1: Wh[b,t,n,o] = sum_f x[b,n,f,t] * W[f,o]   (fused transpose+GEMM)
// Also fused: Wh1[b,t,n] = Wh . a1, Wh2[b,t,n] = Wh . a2
// Block: 256 threads. Tile: 8 n-rows x all 8 t x 128 o. Grid: (N/8, B).
// x[b,n,:,:] is 512 contiguous floats -> fully coalesced LDS staging.
// ---------------------------------------------------------------------------
__global__ __launch_bounds__(256) void k_wh(const float* __restrict__ x,
                                            const float* __restrict__ W,
                                            const float* __restrict__ a,
                                            float* __restrict__ Wh,
                                            float* __restrict__ Wh1,
                                            float* __restrict__ Wh2) {
    __shared__ float  xs[8 * 512];    // [n][f*8+t], 16 KB
    __shared__ float4 Ws4[64 * 32];   // [k][oq] as float4, 32 KB

    const int tid = threadIdx.x;
    const int n0  = blockIdx.x * 8;
    const int b   = blockIdx.y;

    // stage x tile: 8 rows * 512 floats = 1024 float4, coalesced
    const float4* xg4 = (const float4*)(x + (size_t)(b * N_NODES + n0) * (FIN * T_DIM));
    float4* xs4 = (float4*)xs;
    #pragma unroll
    for (int i = 0; i < 4; ++i) xs4[tid + i * 256] = xg4[tid + i * 256];

    // stage W: 64x128 = 2048 float4, coalesced
    const float4* Wg4 = (const float4*)W;
    #pragma unroll
    for (int i = 0; i < 8; ++i) Ws4[tid + i * 256] = Wg4[tid + i * 256];
    __syncthreads();

    const int oq = tid & 31;   // o-quad: o = oq*4 .. oq*4+3
    const int t  = tid >> 5;   // 0..7

    float acc[8][4];
    #pragma unroll
    for (int n = 0; n < 8; ++n) {
        acc[n][0] = 0.f; acc[n][1] = 0.f; acc[n][2] = 0.f; acc[n][3] = 0.f;
    }

    #pragma unroll 4
    for (int k = 0; k < FIN; ++k) {
        float4 w = Ws4[k * 32 + oq];
        #pragma unroll
        for (int n = 0; n < 8; ++n) {
            float xv = xs[n * 512 + k * 8 + t];   // broadcast (2 addrs/wave) - free
            acc[n][0] += xv * w.x;
            acc[n][1] += xv * w.y;
            acc[n][2] += xv * w.z;
            acc[n][3] += xv * w.w;
        }
    }

    const int bt = b * T_DIM + t;

    // store Wh (coalesced float4)
    float4* Whg4 = (float4*)Wh;
    #pragma unroll
    for (int n = 0; n < 8; ++n) {
        float4 v;
        v.x = acc[n][0]; v.y = acc[n][1]; v.z = acc[n][2]; v.w = acc[n][3];
        Whg4[((size_t)bt * N_NODES + (n0 + n)) * 32 + oq] = v;
    }

    // fused Wh1/Wh2: dot over o, reduce across the 32 oq lanes (same half-wave)
    const float4* a4 = (const float4*)a;
    const float4 a1v = a4[oq];        // a[:128]
    const float4 a2v = a4[32 + oq];   // a[128:256]
    #pragma unroll
    for (int n = 0; n < 8; ++n) {
        float s1 = acc[n][0] * a1v.x + acc[n][1] * a1v.y + acc[n][2] * a1v.z + acc[n][3] * a1v.w;
        float s2 = acc[n][0] * a2v.x + acc[n][1] * a2v.y + acc[n][2] * a2v.z + acc[n][3] * a2v.w;
        #pragma unroll
        for (int off = 1; off < 32; off <<= 1) {
            s1 += __shfl_xor(s1, off);
            s2 += __shfl_xor(s2, off);
        }
        if (oq == 0) {
            Wh1[(size_t)bt * N_NODES + n0 + n] = s1;
            Wh2[(size_t)bt * N_NODES + n0 + n] = s2;
        }
    }
}

// ---------------------------------------------------------------------------
// Kernel 2: build neighbor lists from adj (same for all b,t).
// One block per row i. Order within a row is arbitrary (sum order only).
// ---------------------------------------------------------------------------
__global__ __launch_bounds__(256) void k_csr(const float* __restrict__ adj,
                                             int* __restrict__ cnt,
                                             int* __restrict__ nbr) {
    __shared__ int scnt;
    const int i = blockIdx.x;
    if (threadIdx.x == 0) scnt = 0;
    __syncthreads();
    for (int j = threadIdx.x; j < N_NODES; j += 256) {
        if (adj[(size_t)i * N_NODES + j] > 0.0f) {
            int pos = atomicAdd(&scnt, 1);
            if (pos < MAXN) nbr[i * MAXN + pos] = j;
        }
    }
    __syncthreads();
    if (threadIdx.x == 0) cnt[i] = min(scnt, MAXN);
}

// ---------------------------------------------------------------------------
// Kernel 3: sparse softmax + aggregation + ELU + transposed store.
// Block: 512 threads = 8 waves; wave w handles t=w for node i, batch b.
// Grid: (N, B). j-list shared across waves in LDS; output staged through a
// padded LDS tile so the (O,T) block is written fully coalesced.
// ---------------------------------------------------------------------------
__global__ __launch_bounds__(512) void k_agg(const float* __restrict__ Wh,
                                             const float* __restrict__ Wh1,
                                             const float* __restrict__ Wh2,
                                             const int* __restrict__ cnt,
                                             const int* __restrict__ nbr,
                                             float* __restrict__ out) {
    __shared__ int   j_lds[MAXN];                 // 1 KB
    __shared__ float p_lds[T_DIM * MAXN];         // 8 KB
    __shared__ float out_lds[O_DIM * 9];          // 4.5 KB, pad 9 -> conflict-free

    const int tid = threadIdx.x;
    const int w   = tid >> 6;    // wave id = t
    const int l   = tid & 63;    // lane
    const int i   = blockIdx.x;
    const int b   = blockIdx.y;

    const int c = cnt[i];
    for (int jj = tid; jj < c; jj += 512) j_lds[jj] = nbr[i * MAXN + jj];
    __syncthreads();

    const int   t  = w;
    const int   bt = b * T_DIM + t;
    const float h1 = Wh1[(size_t)bt * N_NODES + i];
    const float* wh2row = Wh2 + (size_t)bt * N_NODES;

    // phase A: leaky-relu scores, running max (store e in p_lds)
    float m = -INFINITY;
    for (int jj = l; jj < c; jj += 64) {
        int   j = j_lds[jj];
        float e = h1 + wh2row[j];
        e = e > 0.0f ? e : ALPHA * e;
        p_lds[w * MAXN + jj] = e;
        m = fmaxf(m, e);
    }
    #pragma unroll
    for (int off = 1; off < 64; off <<= 1) m = fmaxf(m, __shfl_xor(m, off));

    // exp + sum (same-lane RAW on p_lds)
    float s = 0.0f;
    for (int jj = l; jj < c; jj += 64) {
        float p = __expf(p_lds[w * MAXN + jj] - m);
        p_lds[w * MAXN + jj] = p;
        s += p;
    }
    #pragma unroll
    for (int off = 1; off < 64; off <<= 1) s += __shfl_xor(s, off);
    const float linv = 1.0f / s;

    __syncthreads();   // cross-lane p_lds visibility (uniform trip counts: safe)

    // phase B: weighted gather of Wh rows. lane l owns channels l and l+64.
    float acc0 = 0.0f, acc1 = 0.0f;
    const float* whbt = Wh + (size_t)bt * N_NODES * O_DIM;
    for (int jj = 0; jj < c; ++jj) {
        int   j = j_lds[jj];
        float p = p_lds[w * MAXN + jj];
        const float* row = whbt + (size_t)j * O_DIM;
        acc0 += p * row[l];
        acc1 += p * row[64 + l];
    }

    float v0 = acc0 * linv, v1 = acc1 * linv;
    v0 = v0 > 0.0f ? v0 : __expf(v0) - 1.0f;     // ELU
    v1 = v1 > 0.0f ? v1 : __expf(v1) - 1.0f;
    out_lds[l * 9 + t]        = v0;
    out_lds[(64 + l) * 9 + t] = v1;
    __syncthreads();

    // out[b,i,o,t]: 1024 contiguous floats per (b,i), coalesced
    float* orow = out + ((size_t)b * N_NODES + i) * (O_DIM * T_DIM);
    for (int idx = tid; idx < O_DIM * T_DIM; idx += 512) {
        orow[idx] = out_lds[(idx >> 3) * 9 + (idx & 7)];
    }
}

// ---------------------------------------------------------------------------
extern "C" void kernel_launch(void* const* d_in, const int* in_sizes, int n_in,
                              void* d_out, int out_size, void* d_ws, size_t ws_size,
                              hipStream_t stream) {
    const float* x   = (const float*)d_in[0];   // (8,1024,64,8)
    const float* adj = (const float*)d_in[1];   // (1024,1024)
    const float* W   = (const float*)d_in[2];   // (64,128)
    const float* a   = (const float*)d_in[3];   // (256,1)
    float* out = (float*)d_out;                 // (8,1024,128,8)

    // workspace carve-up
    float* Wh  = (float*)d_ws;                         // 8*8*1024*128 = 8388608 f
    float* Wh1 = Wh + (size_t)8388608;                 // 65536 f
    float* Wh2 = Wh1 + 65536;                          // 65536 f
    int*   cnt = (int*)(Wh2 + 65536);                  // 1024 i
    int*   nbr = cnt + 1024;                           // 1024*256 i

    k_wh <<<dim3(N_NODES / 8, B_DIM), 256, 0, stream>>>(x, W, a, Wh, Wh1, Wh2);
    k_csr<<<N_NODES, 256, 0, stream>>>(adj, cnt, nbr);
    k_agg<<<dim3(N_NODES, B_DIM), 512, 0, stream>>>(Wh, Wh1, Wh2, cnt, nbr, out);
}